// Round 1
// baseline (253.253 us; speedup 1.0000x reference)
//
#include <hip/hip_runtime.h>

// EMA over time: y_t = 0.1*y_{t-1} + 0.9*x_t, x: [B=16, T=4000, C=512] fp32.
// Chunked-scan: coefficient 0.1 => history beyond W steps contributes < 0.1^W.
// W=16 -> truncation error ~1e-16, below fp32 noise. Each thread scans one
// (b, c4) column over L timesteps with W-step warmup, fully parallel.

constexpr int B_ = 16;
constexpr int T_ = 4000;
constexpr int C_ = 512;
constexpr int L_ = 50;            // timesteps per chunk (T divisible by L)
constexpr int W_ = 16;            // lookback warmup (0.1^16 ~ 1e-16)
constexpr int NC4_ = C_ / 4;      // 128 float4 columns per row
constexpr int NCHUNK_ = (T_ + L_ - 1) / L_;  // 80

__global__ __launch_bounds__(256) void ema_chunk_scan(const float* __restrict__ x,
                                                      float* __restrict__ y) {
    int g = blockIdx.x * blockDim.x + threadIdx.x;
    int c4 = g & (NC4_ - 1);          // lane-major over channels -> coalesced
    int bt = g >> 7;                  // / NC4_
    int b  = bt & (B_ - 1);
    int chunk = bt >> 4;              // / B_
    if (chunk >= NCHUNK_) return;

    int t_write = chunk * L_;
    int t_begin = t_write - W_;
    if (t_begin < 0) t_begin = 0;     // chunk 0: exact from t=0
    int t_end = t_write + L_;
    if (t_end > T_) t_end = T_;

    const float4* p = (const float4*)(x + ((size_t)b * T_ + t_begin) * C_) + c4;
    float4*       q = (float4*)(y + ((size_t)b * T_ + t_write) * C_) + c4;

    const float a = 0.9f, om = 0.1f;
    float4 acc = make_float4(0.f, 0.f, 0.f, 0.f);

    // Warmup: scan lookback window, no stores.
    #pragma unroll 4
    for (int t = t_begin; t < t_write; ++t) {
        float4 xv = *p; p += NC4_;
        acc.x = om * acc.x + a * xv.x;
        acc.y = om * acc.y + a * xv.y;
        acc.z = om * acc.z + a * xv.z;
        acc.w = om * acc.w + a * xv.w;
    }
    // Main: scan + store.
    #pragma unroll 5
    for (int t = t_write; t < t_end; ++t) {
        float4 xv = *p; p += NC4_;
        acc.x = om * acc.x + a * xv.x;
        acc.y = om * acc.y + a * xv.y;
        acc.z = om * acc.z + a * xv.z;
        acc.w = om * acc.w + a * xv.w;
        *q = acc; q += NC4_;
    }
}

extern "C" void kernel_launch(void* const* d_in, const int* in_sizes, int n_in,
                              void* d_out, int out_size, void* d_ws, size_t ws_size,
                              hipStream_t stream) {
    const float* x = (const float*)d_in[0];
    float* y = (float*)d_out;
    int total_threads = B_ * NC4_ * NCHUNK_;   // 163840
    int block = 256;
    int grid = (total_threads + block - 1) / block;  // 640
    ema_chunk_scan<<<grid, block, 0, stream>>>(x, y);
}

// Round 2
// 236.886 us; speedup vs baseline: 1.0691x; 1.0691x over previous
//
#include <hip/hip_runtime.h>

// EMA over time: y_t = 0.1*y_{t-1} + 0.9*x_t, x: [B=16, T=4000, C=512] fp32.
// Chunked-scan: 0.1^8 ~ 1e-8 truncation (threshold 9.6e-2) -> each thread
// scans L=20 steps of one (b, c4) column after an 8-step warmup.
// R2: latency-bound fix — batched register loads (10 outstanding 1KB
// wave-loads) + 2.5x more waves (L 50->20, W 16->8).

constexpr int B_ = 16;
constexpr int T_ = 4000;
constexpr int C_ = 512;
constexpr int L_ = 20;            // timesteps per chunk (T % L == 0)
constexpr int W_ = 8;             // lookback warmup (0.1^8 ~ 1e-8)
constexpr int NC4_ = C_ / 4;      // 128 float4 columns per row
constexpr int NCHUNK_ = T_ / L_;  // 200
constexpr int BATCH_ = 10;        // register-batched loads per inner block

__global__ __launch_bounds__(256, 8) void ema_chunk_scan(const float* __restrict__ x,
                                                         float* __restrict__ y) {
    int g = blockIdx.x * blockDim.x + threadIdx.x;
    int c4 = g & (NC4_ - 1);          // lane-major over channels -> coalesced
    int bt = g >> 7;                  // / NC4_
    int b  = bt & (B_ - 1);
    int chunk = bt >> 4;              // / B_

    int t0 = chunk * L_;
    const float a = 0.9f, om = 0.1f;
    float4 acc = make_float4(0.f, 0.f, 0.f, 0.f);

    // Warmup: 8 independent loads, then FMA chain (no stores).
    if (chunk > 0) {
        const float4* pw = (const float4*)(x + ((size_t)b * T_ + (t0 - W_)) * C_) + c4;
        float4 wbuf[W_];
        #pragma unroll
        for (int i = 0; i < W_; ++i) wbuf[i] = pw[(size_t)i * NC4_];
        #pragma unroll
        for (int i = 0; i < W_; ++i) {
            acc.x = om * acc.x + a * wbuf[i].x;
            acc.y = om * acc.y + a * wbuf[i].y;
            acc.z = om * acc.z + a * wbuf[i].z;
            acc.w = om * acc.w + a * wbuf[i].w;
        }
    }

    // Main: L_=20 steps as 2 batches of 10 (load-all, chain, store-all).
    const float4* pm = (const float4*)(x + ((size_t)b * T_ + t0) * C_) + c4;
    float4*       q  = (float4*)(y + ((size_t)b * T_ + t0) * C_) + c4;
    #pragma unroll
    for (int blk = 0; blk < L_ / BATCH_; ++blk) {
        float4 buf[BATCH_];
        #pragma unroll
        for (int i = 0; i < BATCH_; ++i) buf[i] = pm[(size_t)i * NC4_];
        pm += (size_t)BATCH_ * NC4_;
        #pragma unroll
        for (int i = 0; i < BATCH_; ++i) {
            acc.x = om * acc.x + a * buf[i].x;
            acc.y = om * acc.y + a * buf[i].y;
            acc.z = om * acc.z + a * buf[i].z;
            acc.w = om * acc.w + a * buf[i].w;
            buf[i] = acc;
        }
        #pragma unroll
        for (int i = 0; i < BATCH_; ++i) q[(size_t)i * NC4_] = buf[i];
        q += (size_t)BATCH_ * NC4_;
    }
}

extern "C" void kernel_launch(void* const* d_in, const int* in_sizes, int n_in,
                              void* d_out, int out_size, void* d_ws, size_t ws_size,
                              hipStream_t stream) {
    const float* x = (const float*)d_in[0];
    float* y = (float*)d_out;
    int total_threads = B_ * NC4_ * NCHUNK_;   // 409600
    int block = 256;
    int grid = total_threads / block;          // 1600
    ema_chunk_scan<<<grid, block, 0, stream>>>(x, y);
}

// Round 3
// 228.580 us; speedup vs baseline: 1.1079x; 1.0363x over previous
//
#include <hip/hip_runtime.h>

// EMA over time: y_t = 0.1*y_{t-1} + 0.9*x_t, x: [B=16, T=4000, C=512] fp32.
// Chunked-scan: 0.1^8 ~ 1e-8 truncation (threshold 9.6e-2). Each thread owns
// one (b, c4) column for L=8 timesteps, warming up over the previous W=8.
// R3: issue ALL 16 independent float4 loads before any use (max MLP),
// __launch_bounds__(256,4) so the register allocator keeps them live
// (R2's (256,8) cap collapsed the batch to ~4 outstanding -> 2.6 TB/s).
// Branch-free warmup: chunk 0 loads x[0..7] and zeroes the warmup acc.

constexpr int B_ = 16;
constexpr int T_ = 4000;
constexpr int C_ = 512;
constexpr int L_ = 8;             // output timesteps per thread
constexpr int W_ = 8;             // lookback warmup (0.1^8 ~ 1e-8)
constexpr int NC4_ = C_ / 4;      // 128 float4 columns per row
constexpr int NCHUNK_ = T_ / L_;  // 500

__global__ __launch_bounds__(256, 4) void ema_chunk_scan(const float* __restrict__ x,
                                                         float* __restrict__ y) {
    int g = blockIdx.x * blockDim.x + threadIdx.x;
    int c4 = g & (NC4_ - 1);          // lane-major over channels -> coalesced
    int bt = g >> 7;                  // / NC4_
    int b  = bt & (B_ - 1);
    int chunk = bt >> 4;              // / B_  (wave-uniform)

    int t0 = chunk * L_;
    int tw = (chunk > 0) ? (t0 - W_) : 0;

    const float4* pw = (const float4*)(x + ((size_t)b * T_ + tw) * C_) + c4;
    const float4* pm = (const float4*)(x + ((size_t)b * T_ + t0) * C_) + c4;
    float4*       q  = (float4*)(y + ((size_t)b * T_ + t0) * C_) + c4;

    // ---- issue all 16 loads before any use ----
    float4 w[W_];
    #pragma unroll
    for (int i = 0; i < W_; ++i) w[i] = pw[(size_t)i * NC4_];
    float4 m[L_];
    #pragma unroll
    for (int i = 0; i < L_; ++i) m[i] = pm[(size_t)i * NC4_];

    const float a = 0.9f, om = 0.1f;
    float4 acc = make_float4(0.f, 0.f, 0.f, 0.f);

    // Warmup chain (no stores).
    #pragma unroll
    for (int i = 0; i < W_; ++i) {
        acc.x = om * acc.x + a * w[i].x;
        acc.y = om * acc.y + a * w[i].y;
        acc.z = om * acc.z + a * w[i].z;
        acc.w = om * acc.w + a * w[i].w;
    }
    // chunk 0: no history — zero the warmup state (wave-uniform select).
    float sel = (chunk > 0) ? 1.f : 0.f;
    acc.x *= sel; acc.y *= sel; acc.z *= sel; acc.w *= sel;

    // Main chain: store each result as soon as it's produced.
    #pragma unroll
    for (int i = 0; i < L_; ++i) {
        acc.x = om * acc.x + a * m[i].x;
        acc.y = om * acc.y + a * m[i].y;
        acc.z = om * acc.z + a * m[i].z;
        acc.w = om * acc.w + a * m[i].w;
        q[(size_t)i * NC4_] = acc;
    }
}

extern "C" void kernel_launch(void* const* d_in, const int* in_sizes, int n_in,
                              void* d_out, int out_size, void* d_ws, size_t ws_size,
                              hipStream_t stream) {
    const float* x = (const float*)d_in[0];
    float* y = (float*)d_out;
    int total_threads = B_ * NC4_ * NCHUNK_;   // 1,024,000
    int block = 256;
    int grid = total_threads / block;          // 4000
    ema_chunk_scan<<<grid, block, 0, stream>>>(x, y);
}